// Round 3
// baseline (237.884 us; speedup 1.0000x reference)
//
#include <hip/hip_runtime.h>

#define B_ 32
#define C_ 128
#define H_ 56
#define W_ 56
#define HW_ (H_*W_)            // 3136
#define SIZE_ (C_*HW_)         // 401408
#define NPIX_ (B_*HW_)         // 100352 = 784 * 128
#define HP_ 58
#define WP_ 58
#define PLANE_ (HP_*WP_*C_)    // 430592 bf16 elements per batch plane
#define K_ 1152                // 9 * 128
#define EPS_ 1e-5f
#define SLOPE_ 0.1f

typedef __bf16 bf16x8 __attribute__((ext_vector_type(8)));
typedef float  f32x4  __attribute__((ext_vector_type(4)));

__device__ __forceinline__ ushort f2bf(float x) {
    union { float f; unsigned u; } v; v.f = x;
    return (ushort)((v.u + 0x7FFFu + ((v.u >> 16) & 1u)) >> 16);   // RNE
}
__device__ __forceinline__ float lrelu(float z) { return z > 0.f ? z : SLOPE_ * z; }

// async global->LDS, 16B per lane; LDS dest = wave-uniform base + lane*16
__device__ __forceinline__ void glds16(const ushort* g, ushort* l) {
    __builtin_amdgcn_global_load_lds(
        (const __attribute__((address_space(1))) unsigned int*)g,
        (__attribute__((address_space(3))) unsigned int*)l, 16, 0, 0);
}

// ---------------------------------------------------------------------------
// prep: repack conv_w -> bf16 wA[co][k], k=(kh*3+kw)*128+ci; fold bias+BN2;
//       fold BN1 into per-position mix params p0,p1,p2.
// ---------------------------------------------------------------------------
__global__ __launch_bounds__(256) void prep_kernel(
    const float* __restrict__ conv_w, const float* __restrict__ conv_b,
    const float* __restrict__ g2, const float* __restrict__ b2,
    const float* __restrict__ m2, const float* __restrict__ v2,
    const float2* __restrict__ cfc, const float* __restrict__ g1,
    const float* __restrict__ b1, const float* __restrict__ mu1,
    const float* __restrict__ v1,
    ushort* __restrict__ wA, float* __restrict__ scale2, float* __restrict__ shift2,
    float* __restrict__ p0, float* __restrict__ p1, float* __restrict__ p2)
{
    int tid = blockIdx.x * 256 + threadIdx.x;
    if (tid < C_ * K_) {
        int co = tid / K_;
        int k  = tid - co * K_;
        int khkw = k >> 7, ci = k & 127;
        int kh = khkw / 3, kw = khkw - 3 * kh;
        wA[tid] = f2bf(conv_w[((co * C_ + ci) * 3 + kh) * 3 + kw]);
    }
    if (tid < C_) {
        float sc = g2[tid] * rsqrtf(v2[tid] + EPS_);
        scale2[tid] = sc;
        shift2[tid] = (conv_b[tid] - m2[tid]) * sc + b2[tid];
    }
    if (tid < SIZE_) {
        float sc = g1[tid] * rsqrtf(v1[tid] + EPS_);
        float2 wv = cfc[tid];
        p0[tid] = wv.x * sc;
        p1[tid] = wv.y * sc;
        p2[tid] = b1[tid] - mu1[tid] * sc;
    }
}

// ---------------------------------------------------------------------------
// zfuse: z = leaky(a*p0 + m*p1 + p2) -> bf16 NHWC zero-padded [32][58][58][128]
// LDS transpose in [c][w] stride-58 layout: packed uint writes (~2-way),
// scalar u16 gather reads (cheap), coalesced uint2 global stores.
// ---------------------------------------------------------------------------
__global__ __launch_bounds__(256) void zfuse_kernel(
    const float4* __restrict__ ax, const float4* __restrict__ mx,
    const float4* __restrict__ p0, const float4* __restrict__ p1,
    const float4* __restrict__ p2, ushort* __restrict__ zp)
{
    __shared__ ushort tile[C_ * 58];           // [c][w], stride 58 (anti-conflict)
    const int hp = blockIdx.x, b = blockIdx.y;
    const int tid = threadIdx.x;
    ushort* row = zp + (size_t)b * PLANE_ + (size_t)hp * (WP_ * C_);
    if (hp == 0 || hp == HP_ - 1) {            // full zero border rows
        uint2* r2 = (uint2*)row;
        for (int i = tid; i < WP_ * C_ / 4; i += 256) r2[i] = make_uint2(0u, 0u);
        return;
    }
    const int h = hp - 1;
    const int base4 = (b * SIZE_) >> 2;
    for (int i = tid; i < 1792; i += 256) {    // 128 c * 14 float4-groups
        int c  = i / 14;
        int w4 = i - c * 14;
        int s4 = c * (HW_ / 4) + h * (W_ / 4) + w4;   // float4 index into [SIZE_]
        float4 a = ax[base4 + s4];
        float4 m = mx[base4 + s4];
        float4 q0 = p0[s4], q1 = p1[s4], q2 = p2[s4];
        uint z0 = f2bf(lrelu(a.x * q0.x + m.x * q1.x + q2.x));
        uint z1 = f2bf(lrelu(a.y * q0.y + m.y * q1.y + q2.y));
        uint z2 = f2bf(lrelu(a.z * q0.z + m.z * q1.z + q2.z));
        uint z3 = f2bf(lrelu(a.w * q0.w + m.w * q1.w + q2.w));
        uint* t32 = (uint*)(tile + c * 58 + w4 * 4);  // byte 116c+8w4: 4B-aligned
        t32[0] = z0 | (z1 << 16);
        t32[1] = z2 | (z3 << 16);
    }
    __syncthreads();
    if (tid < 64) {                            // left/right border columns (w=0,57)
        int side = tid >> 5, cc = tid & 31;
        *(uint2*)(row + side * (57 * C_) + cc * 4) = make_uint2(0u, 0u);
    }
    for (int j = tid; j < 1792; j += 256) {    // 56 w * 32 c-groups of 4
        int w  = j >> 5;
        int c0 = (j & 31) * 4;
        uint lo = (uint)tile[(c0 + 0) * 58 + w] | ((uint)tile[(c0 + 1) * 58 + w] << 16);
        uint hi = (uint)tile[(c0 + 2) * 58 + w] | ((uint)tile[(c0 + 3) * 58 + w] << 16);
        *(uint2*)(row + (w + 1) * C_ + c0) = make_uint2(lo, hi);
    }
}

// ---------------------------------------------------------------------------
// conv: implicit GEMM, M=128co x N=100352px x K=1152, bf16 MFMA 16x16x32.
// 128x128 tile, BK=32, DOUBLE-buffered 2x16KB LDS, global_load_lds width=16.
// XOR chunk swizzle kills the 8-way ds_read_b128 bank conflicts.
// XCD-swizzled block index: each XCD covers a contiguous 3.4MB zp span.
// ---------------------------------------------------------------------------
__global__ __launch_bounds__(256) void conv_kernel(
    const ushort* __restrict__ zp, const ushort* __restrict__ wA,
    const float* __restrict__ scale2, const float* __restrict__ shift2,
    float* __restrict__ out)
{
    __shared__ ushort As[2 * 4096];   // [buf][co(128)][32]
    __shared__ ushort Bs[2 * 4096];   // [buf][px(128)][32]

    const int tid  = threadIdx.x;
    const int wave = tid >> 6, lane = tid & 63;
    const int l16  = lane & 15, quad = lane >> 4;
    const int blk  = blockIdx.x;                       // 784 = 8 XCDs * 98
    const int pbase = ((blk & 7) * 98 + (blk >> 3)) * 128;

    // ---- staging roles: wave stages 32 rows; chunk XOR-swizzled by row ----
    const int srow = wave * 32 + (lane >> 2);          // rows +0..15 (+16 for 2nd)
    const int sch  = (lane & 3) ^ ((lane >> 3) & 3);   // chunk ^ ((row>>1)&3)
    const ushort* agA0 = wA + srow * K_ + sch * 8;

    int pf0 = pbase + srow;
    int bb0 = pf0 / HW_, pi0 = pf0 - bb0 * HW_;
    int h0 = pi0 / W_, w0 = pi0 - h0 * W_;
    const ushort* bgB0 = zp + (size_t)bb0 * PLANE_ + (h0 * WP_ + w0) * C_ + sch * 8;
    int pf1 = pf0 + 16;
    int bb1 = pf1 / HW_, pi1 = pf1 - bb1 * HW_;
    int h1 = pi1 / W_, w1 = pi1 - h1 * W_;
    const ushort* bgB1 = zp + (size_t)bb1 * PLANE_ + (h1 * WP_ + w1) * C_ + sch * 8;

    ushort* aD = As + wave * 1024;                     // wave-uniform LDS dests
    ushort* bD = Bs + wave * 1024;

    auto stage = [&](int s, int buf) {
        int tap = s >> 2;
        int ko  = (s & 3) * 32;
        int kh  = tap / 3, kw = tap - 3 * kh;
        int aoff = tap * C_ + ko;
        int boff = (kh * WP_ + kw) * C_ + ko;          // wave-uniform tap offset
        glds16(agA0 + aoff,           aD + buf * 4096);
        glds16(agA0 + 16 * K_ + aoff, aD + buf * 4096 + 512);
        glds16(bgB0 + boff,           bD + buf * 4096);
        glds16(bgB1 + boff,           bD + buf * 4096 + 512);
    };

    // ---- compute roles: wave = 64co x 64px quadrant ----
    const int cob = (wave & 1) * 64;
    const int pxb = (wave >> 1) * 64;
    const int swq = (quad ^ ((l16 >> 1) & 3)) * 8;     // swizzled chunk position

    f32x4 acc[4][4] = {};
    stage(0, 0);
    #pragma unroll 2
    for (int s = 0; s < 36; ++s) {
        const int cur = s & 1;
        __syncthreads();                  // waits own vmcnt(0): buf[cur] staged;
                                          // all waves done reading buf[cur^1]
        if (s < 35) stage(s + 1, cur ^ 1);
        const ushort* Ab = As + cur * 4096;
        const ushort* Bb = Bs + cur * 4096;
        bf16x8 af[4], bfr[4];
        #pragma unroll
        for (int mt = 0; mt < 4; ++mt)
            af[mt] = *(const bf16x8*)(Ab + (cob + mt * 16 + l16) * 32 + swq);
        #pragma unroll
        for (int nt = 0; nt < 4; ++nt)
            bfr[nt] = *(const bf16x8*)(Bb + (pxb + nt * 16 + l16) * 32 + swq);
        #pragma unroll
        for (int mt = 0; mt < 4; ++mt)
            #pragma unroll
            for (int nt = 0; nt < 4; ++nt)
                acc[mt][nt] = __builtin_amdgcn_mfma_f32_16x16x32_bf16(
                    af[mt], bfr[nt], acc[mt][nt], 0, 0, 0);
    }

    // ---- epilogue: fused scale/shift + leaky, NCHW fp32 stores ----
    int pob[4];
    #pragma unroll
    for (int nt = 0; nt < 4; ++nt) {
        int pf = pbase + pxb + nt * 16 + l16;
        int bb = pf / HW_;
        pob[nt] = bb * SIZE_ + (pf - bb * HW_);
    }
    #pragma unroll
    for (int mt = 0; mt < 4; ++mt) {
        #pragma unroll
        for (int r = 0; r < 4; ++r) {
            int co = cob + mt * 16 + quad * 4 + r;
            float sc = scale2[co], sh = shift2[co];
            #pragma unroll
            for (int nt = 0; nt < 4; ++nt) {
                float v = acc[mt][nt][r] * sc + sh;
                out[(size_t)pob[nt] + co * HW_] = lrelu(v);
            }
        }
    }
}

// ---------------------------------------------------------------------------
extern "C" void kernel_launch(void* const* d_in, const int* in_sizes, int n_in,
                              void* d_out, int out_size, void* d_ws, size_t ws_size,
                              hipStream_t stream) {
    const float* ax     = (const float*)d_in[0];
    const float* mx     = (const float*)d_in[1];
    const float* cfc    = (const float*)d_in[2];
    const float* bn_g   = (const float*)d_in[3];
    const float* bn_b   = (const float*)d_in[4];
    const float* bn_m   = (const float*)d_in[5];
    const float* bn_v   = (const float*)d_in[6];
    const float* conv_w = (const float*)d_in[7];
    const float* conv_b = (const float*)d_in[8];
    const float* g2     = (const float*)d_in[9];
    const float* b2     = (const float*)d_in[10];
    const float* m2     = (const float*)d_in[11];
    const float* v2     = (const float*)d_in[12];
    float* out = (float*)d_out;

    char* ws = (char*)d_ws;
    // zp: 27,557,888 B | wA: 294,912 B | scale2/shift2: 512 B | p0/p1/p2: 1,605,632 B each
    ushort* zp     = (ushort*)ws;
    ushort* wA     = (ushort*)(ws + 27557888);
    float*  scale2 = (float*)(ws + 27852800);
    float*  shift2 = (float*)(ws + 27853312);
    float*  p0     = (float*)(ws + 27853824);
    float*  p1     = (float*)(ws + 29459456);
    float*  p2     = (float*)(ws + 31065088);

    prep_kernel<<<dim3((SIZE_ + 255) / 256), 256, 0, stream>>>(
        conv_w, conv_b, g2, b2, m2, v2, (const float2*)cfc,
        bn_g, bn_b, bn_m, bn_v, wA, scale2, shift2, p0, p1, p2);
    zfuse_kernel<<<dim3(HP_, B_), 256, 0, stream>>>(
        (const float4*)ax, (const float4*)mx,
        (const float4*)p0, (const float4*)p1, (const float4*)p2, zp);
    conv_kernel<<<dim3(NPIX_ / 128), 256, 0, stream>>>(zp, wA, scale2, shift2, out);
}